// Round 16
// baseline (1254.163 us; speedup 1.0000x reference)
//
#include <hip/hip_runtime.h>

typedef unsigned short u16;
typedef unsigned int u32;
typedef __bf16 bf16x8 __attribute__((ext_vector_type(8)));
typedef float f32x4 __attribute__((ext_vector_type(4)));

#define MFMA16(a, b, c) __builtin_amdgcn_mfma_f32_16x16x32_bf16((a), (b), (c), 0, 0, 0)

__device__ __forceinline__ u16 f2bf(float x) {
    union { float f; u32 u; } v; v.f = x;
    u32 r = v.u + 0x7fffu + ((v.u >> 16) & 1u);
    return (u16)(r >> 16);
}
__device__ __forceinline__ float bf2f(u16 x) {
    union { u32 u; float f; } v; v.u = ((u32)x) << 16; return v.f;
}

typedef const __attribute__((address_space(1))) u32* gas1_t;
typedef __attribute__((address_space(3))) u32* las3_t;
__device__ __forceinline__ void g2lds16(const void* g, void* l) {
    __builtin_amdgcn_global_load_lds((gas1_t)g, (las3_t)l, 16, 0, 0);
}

// ---------------------------------------------------------------------------
// GEMM: m97 fragment layout + 2-phase dbuf staging + dead-tile skip +
// balanced XCD mapping (xcd(tm)=(tm+batch)&7, bijective for gy%16==0).
// BK=32 (wide N): r8 loop + rule-21 swizzle (0 conflicts, measured r12/r15).
// BK=64 (narrow N=512): r8 path w/ its swizzle (0 conflicts, measured r10).
// MODE 1/3 epilogue: repack C-tile through (now-dead) staging LDS with
//   16B-granule XOR swizzle -> 8 coalesced uint4 stores/thread instead of
//   64 scalar u16 stores (write-transaction + VMEM-issue fix).
// MODE 0: +=PE, f32+bf16 out. 1: bf16. 2: +=resid, f32. 3: relu bf16.
// ---------------------------------------------------------------------------
template <int MODE, int BK>
__global__ __launch_bounds__(256) void gemm_bf16(
    const u16* __restrict__ A, const u16* __restrict__ BT,
    const float* __restrict__ bias, float* __restrict__ outF,
    u16* __restrict__ outB, const float* __restrict__ aux,
    const int* __restrict__ obs,
    int M, int N, int K)
{
    __shared__ u16 SH[4][128 * BK];   // As = SH[0..1], Bs = SH[2..3]; >=32KB
    const int tid = threadIdx.x;
    const int w = tid >> 6, l = tid & 63;
    const int gx = gridDim.x, gy = gridDim.y;
    const int orig = blockIdx.y * gx + blockIdx.x;
    int tm, tn;
    if ((gy & 15) == 0) {
        const int xcd = orig & 7;
        const int loc = orig >> 3;
        tn = loc % gx;
        const int j = loc / gx;
        const int bb = j >> 1;
        tm = bb * 16 + ((xcd - bb) & 7) + ((j & 1) << 3);
    } else {
        tm = blockIdx.y; tn = blockIdx.x;
    }
    const int bm = tm * 128, bn = tn * 128;
    if ((bm & 2047) > obs[bm >> 11]) return;   // dead tile (pad rows only)
    const int wr = (w >> 1) * 64, wc = (w & 1) * 64;
    f32x4 acc[4][4] = {};
    const int lane15 = l & 15, lhi = l >> 4;

    // --- staging (linear LDS dest + pre-swizzled global source, rule 21) ---
    const int larow = l >> 2;                                     // BK=32
    const int lacol = (((l & 3) ^ ((l >> 3) & 3)) << 3);
    const int gsw32 = ((lhi ^ ((lane15 >> 1) & 3)) << 3);
    const int r0a = 16 * w, r0b = 16 * (w + 4);
    const u16* Ap = &A[(size_t)(bm + larow) * K + lacol];
    const u16* Bp = &BT[(size_t)(bn + larow) * K + lacol];
    const int srow = l >> 3;                                      // BK=64
    const int scol = ((l & 7) ^ srow) << 3;

    auto STAGE = [&](int buf, int kt) {
        if constexpr (BK == 32) {
            g2lds16(Ap + (size_t)r0a * K + kt, &SH[buf][r0a * 32]);
            g2lds16(Bp + (size_t)r0a * K + kt, &SH[2 + buf][r0a * 32]);
            g2lds16(Ap + (size_t)r0b * K + kt, &SH[buf][r0b * 32]);
            g2lds16(Bp + (size_t)r0b * K + kt, &SH[2 + buf][r0b * 32]);
        } else {
            #pragma unroll
            for (int q = 0; q < 4; ++q) {
                const int rr = w * 32 + q * 8;
                g2lds16(&A[(size_t)(bm + rr + srow) * K + kt + scol], &SH[buf][rr * 64]);
                g2lds16(&BT[(size_t)(bn + rr + srow) * K + kt + scol], &SH[2 + buf][rr * 64]);
            }
        }
    };

    STAGE(0, 0);
    __syncthreads();
    int cur = 0;
    const int nk = K / BK;
    for (int ki = 0; ki < nk; ++ki) {
        if (ki + 1 < nk) STAGE(cur ^ 1, (ki + 1) * BK);
        if constexpr (BK == 32) {
            bf16x8 af[4], bfr[4];
            #pragma unroll
            for (int i = 0; i < 4; ++i)
                af[i] = *(const bf16x8*)&SH[cur][(wr + i * 16 + lane15) * 32 + gsw32];
            #pragma unroll
            for (int j = 0; j < 4; ++j)
                bfr[j] = *(const bf16x8*)&SH[2 + cur][(wc + j * 16 + lane15) * 32 + gsw32];
            #pragma unroll
            for (int i = 0; i < 4; ++i)
                #pragma unroll
                for (int j = 0; j < 4; ++j)
                    acc[i][j] = MFMA16(af[i], bfr[j], acc[i][j]);
        } else {
            #pragma unroll
            for (int kk = 0; kk < 2; ++kk) {
                const int gsw = ((kk * 4 + lhi) ^ (l & 7)) << 3;
                bf16x8 af[4], bfr[4];
                #pragma unroll
                for (int i = 0; i < 4; ++i)
                    af[i] = *(const bf16x8*)&SH[cur][(wr + i * 16 + lane15) * 64 + gsw];
                #pragma unroll
                for (int j = 0; j < 4; ++j)
                    bfr[j] = *(const bf16x8*)&SH[2 + cur][(wc + j * 16 + lane15) * 64 + gsw];
                #pragma unroll
                for (int i = 0; i < 4; ++i)
                    #pragma unroll
                    for (int j = 0; j < 4; ++j)
                        acc[i][j] = MFMA16(af[i], bfr[j], acc[i][j]);
            }
        }
        __syncthreads();
        cur ^= 1;
    }

    if constexpr (MODE == 1 || MODE == 3) {
        // LDS-repack epilogue: staging LDS is dead after the final barrier.
        u16* Cs = &SH[0][0];   // 32KB = 128x128 bf16 tile
        #pragma unroll
        for (int i = 0; i < 4; ++i) {
            #pragma unroll
            for (int j = 0; j < 4; ++j) {
                const int cl = wc + j * 16 + lane15;
                const float bc = bias[bn + cl];
                const int gq = cl >> 3;                 // 16B granule 0..15
                #pragma unroll
                for (int r = 0; r < 4; ++r) {
                    const int rl = wr + i * 16 + lhi * 4 + r;
                    float val = acc[i][j][r] + bc;
                    if constexpr (MODE == 3) val = fmaxf(val, 0.f);
                    const int pos = (gq & 8) | ((gq ^ rl) & 7);
                    Cs[rl * 128 + pos * 8 + (cl & 7)] = f2bf(val);
                }
            }
        }
        __syncthreads();
        {
            const int row = tid & 127, h = tid >> 7;
            const size_t gbase = (size_t)(bm + row) * N + bn + h * 64;
            #pragma unroll
            for (int k = 0; k < 8; ++k) {
                const int g = h * 8 + k;
                const int pos = (g & 8) | ((g ^ row) & 7);
                uint4 v = *(const uint4*)&Cs[row * 128 + pos * 8];
                *(uint4*)&outB[gbase + k * 8] = v;
            }
        }
    } else {
        const int r0 = bm + wr + lhi * 4;
        const int c0 = bn + wc + lane15;
        #pragma unroll
        for (int i = 0; i < 4; ++i) {
            #pragma unroll
            for (int j = 0; j < 4; ++j) {
                const int col = c0 + j * 16;
                const float bc = bias[col];
                #pragma unroll
                for (int r = 0; r < 4; ++r) {
                    const int row = r0 + i * 16 + r;
                    const size_t idx = (size_t)row * N + col;
                    float val = acc[i][j][r] + bc;
                    if constexpr (MODE == 0) {
                        val += aux[(size_t)(row & 2047) * 512 + col];
                        outF[idx] = val;
                        outB[idx] = f2bf(val);
                    } else {
                        outF[idx] = val + aux[idx];
                    }
                }
            }
        }
    }
}

__global__ void pe_kernel(float* __restrict__ PE) {
    const int idx = blockIdx.x * 256 + threadIdx.x;
    const int t = idx >> 8, p = idx & 255;
    const float fr = expf((float)(2 * p) * -0.017988946039015984f);
    const float arg = (float)t * fr;
    float s, c;
    sincosf(arg, &s, &c);
    float2 v = {s, c};
    *(float2*)&PE[(size_t)t * 512 + 2 * p] = v;
}

// ---------------------------------------------------------------------------
// Flash attention (round-8 version, unchanged).
// ---------------------------------------------------------------------------
__global__ __launch_bounds__(256) void attn_kernel(
    const u16* __restrict__ QKV, u16* __restrict__ CTX, const int* __restrict__ obs,
    float* __restrict__ PBm, float* __restrict__ PBl, float* __restrict__ PBo)
{
    __shared__ u16 Ks[64 * 64];
    __shared__ u16 Vt[64 * 64];
    __shared__ u16 Ps[4][16 * 64];
    const int b = blockIdx.z, h = blockIdx.y;
    const int L = obs[b];
    const int tid = threadIdx.x, w = tid >> 6, l = tid & 63;
    const size_t tb = (size_t)b * 2048;

    if (blockIdx.x >= 32) {
        const int cbase = (blockIdx.x - 32) * 4;
        if (cbase * 64 > L) return;
        const int cc = cbase + w;
        float* pP = (float*)Ks;
        u16 q16[64];
        #pragma unroll
        for (int dd = 0; dd < 8; ++dd)
            *(uint4*)&q16[dd * 8] = *(const uint4*)&QKV[(tb + L) * 1536 + h * 64 + dd * 8];
        const int j = cc * 64 + l;
        const bool val = (j <= L);
        float s = -3.0e38f;
        if (val) {
            s = 0.f;
            const u16* kp = &QKV[(tb + j) * 1536 + 512 + h * 64];
            #pragma unroll
            for (int dd = 0; dd < 8; ++dd) {
                uint4 kk = *(const uint4*)&kp[dd * 8];
                const u16* ke = (const u16*)&kk;
                #pragma unroll
                for (int e = 0; e < 8; ++e)
                    s += bf2f(q16[dd * 8 + e]) * bf2f(ke[e]);
            }
            s *= 0.125f;
        }
        float mx = s;
        #pragma unroll
        for (int d = 1; d < 64; d <<= 1) mx = fmaxf(mx, __shfl_xor(mx, d, 64));
        const float p = val ? __expf(s - mx) : 0.f;
        float ps = p;
        #pragma unroll
        for (int d = 1; d < 64; d <<= 1) ps += __shfl_xor(ps, d, 64);
        pP[w * 64 + l] = p;
        __builtin_amdgcn_wave_barrier();
        if (cc * 64 <= L) {
            float oacc = 0.f;
            #pragma unroll 4
            for (int jj = 0; jj < 64; ++jj) {
                const int key = cc * 64 + jj;
                const int rr = (key <= L) ? key : L;
                oacc += pP[w * 64 + jj] * bf2f(QKV[(tb + rr) * 1536 + 1024 + h * 64 + l]);
            }
            const int pidx = (b * 8 + h) * 32 + cc;
            PBo[(size_t)pidx * 64 + l] = oacc;
            if (l == 0) { PBm[pidx] = mx; PBl[pidx] = ps; }
        }
        return;
    }

    const int i0 = blockIdx.x * 64;
    if (i0 > L) return;

    bf16x8 qa0, qa1;
    {
        const int qrow = i0 + 16 * w + (l & 15);
        const u16* qp = &QKV[(tb + qrow) * 1536 + h * 64];
        qa0 = *(const bf16x8*)(qp + 8 * (l >> 4));
        qa1 = *(const bf16x8*)(qp + 32 + 8 * (l >> 4));
    }
    const int g0 = (l >> 4) ^ (l & 7);
    const int g1 = ((l >> 4) + 4) ^ (l & 7);

    float m_r[4] = {-1e30f, -1e30f, -1e30f, -1e30f};
    float l_r[4] = {0.f, 0.f, 0.f, 0.f};
    f32x4 acc_o[4] = {};
    const int klo = (i0 >= 128) ? (i0 - 64) : 0;
    int khi = (L < klo) ? klo : min(i0 + 63, L);

    for (int j0 = klo; j0 <= khi; j0 += 64) {
        __syncthreads();
        {
            const int krow0 = 8 * w + (l >> 3);
            const int kswz = ((l & 7) ^ (l >> 3)) << 3;
            #pragma unroll
            for (int q = 0; q < 2; ++q) {
                const int row = krow0 + 32 * q;
                g2lds16(&QKV[(tb + j0 + row) * 1536 + 512 + h * 64 + kswz],
                        &Ks[(8 * w + 32 * q) * 64]);
            }
            const int vr = tid >> 3, c8 = (tid & 7) * 8;
            #pragma unroll
            for (int q = 0; q < 2; ++q) {
                const int row = vr + 32 * q;
                uint4 vv = *(const uint4*)&QKV[(tb + j0 + row) * 1536 + 1024 + h * 64 + c8];
                const u16* vs = (const u16*)&vv;
                #pragma unroll
                for (int e = 0; e < 8; ++e) {
                    const int d = c8 + e;
                    Vt[d * 64 + (((row >> 3) ^ e) << 3) + (row & 7)] = vs[e];
                }
            }
        }
        __syncthreads();
        f32x4 s[4];
        #pragma unroll
        for (int f = 0; f < 4; ++f) {
            f32x4 z = {0.f, 0.f, 0.f, 0.f};
            const int rowk = (f * 16 + (l & 15)) * 64;
            bf16x8 kb0 = *(const bf16x8*)&Ks[rowk + g0 * 8];
            bf16x8 kb1 = *(const bf16x8*)&Ks[rowk + g1 * 8];
            z = MFMA16(qa0, kb0, z);
            z = MFMA16(qa1, kb1, z);
            s[f] = z;
        }
        float pm[4];
        #pragma unroll
        for (int r = 0; r < 4; ++r) {
            const int i_r = i0 + 16 * w + (l >> 4) * 4 + r;
            float mx = -__builtin_inff();
            #pragma unroll
            for (int f = 0; f < 4; ++f) {
                const int j = j0 + f * 16 + (l & 15);
                float sv = s[f][r] * 0.125f;
                const bool ok = (i_r >= L) ? (j == klo)
                              : (j <= i_r && (i_r <= 64 || j >= i_r - 64));
                sv = ok ? sv : -__builtin_inff();
                s[f][r] = sv;
                mx = fmaxf(mx, sv);
            }
            pm[r] = mx;
        }
        #pragma unroll
        for (int d = 1; d < 16; d <<= 1)
            #pragma unroll
            for (int r = 0; r < 4; ++r) pm[r] = fmaxf(pm[r], __shfl_xor(pm[r], d, 64));
        float sc[4];
        #pragma unroll
        for (int r = 0; r < 4; ++r) {
            const float mn = fmaxf(m_r[r], fmaxf(pm[r], -1e30f));
            sc[r] = __expf(m_r[r] - mn);
            m_r[r] = mn;
            l_r[r] *= sc[r];
        }
        #pragma unroll
        for (int f = 0; f < 4; ++f)
            #pragma unroll
            for (int r = 0; r < 4; ++r) acc_o[f][r] *= sc[r];
        float ps[4] = {0.f, 0.f, 0.f, 0.f};
        #pragma unroll
        for (int f = 0; f < 4; ++f)
            #pragma unroll
            for (int r = 0; r < 4; ++r) {
                const float p = __expf(s[f][r] - m_r[r]);
                s[f][r] = p;
                ps[r] += p;
            }
        #pragma unroll
        for (int d = 1; d < 16; d <<= 1)
            #pragma unroll
            for (int r = 0; r < 4; ++r) ps[r] += __shfl_xor(ps[r], d, 64);
        #pragma unroll
        for (int r = 0; r < 4; ++r) l_r[r] += ps[r];
        {
            const int cg = ((l >> 3) & 1);
            #pragma unroll
            for (int f = 0; f < 4; ++f)
                #pragma unroll
                for (int r = 0; r < 4; ++r) {
                    const int prow = (l >> 4) * 4 + r;
                    Ps[w][prow * 64 + (((f * 2 + cg) ^ (prow & 7)) << 3) + (l & 7)] =
                        f2bf(s[f][r]);
                }
        }
        bf16x8 pa0 = *(const bf16x8*)&Ps[w][(l & 15) * 64 + g0 * 8];
        bf16x8 pa1 = *(const bf16x8*)&Ps[w][(l & 15) * 64 + g1 * 8];
        #pragma unroll
        for (int f = 0; f < 4; ++f) {
            const int dv = (f * 16 + (l & 15)) * 64;
            bf16x8 vb0 = *(const bf16x8*)&Vt[dv + g0 * 8];
            bf16x8 vb1 = *(const bf16x8*)&Vt[dv + g1 * 8];
            acc_o[f] = MFMA16(pa0, vb0, acc_o[f]);
            acc_o[f] = MFMA16(pa1, vb1, acc_o[f]);
        }
    }
    #pragma unroll
    for (int r = 0; r < 4; ++r) {
        const float inv = 1.f / l_r[r];
        const int row = i0 + 16 * w + (l >> 4) * 4 + r;
        if (row != L) {
            #pragma unroll
            for (int f = 0; f < 4; ++f)
                CTX[(tb + row) * 512 + h * 64 + f * 16 + (l & 15)] = f2bf(acc_o[f][r] * inv);
        }
    }
}

__global__ void attn_merge(const float* __restrict__ PBm, const float* __restrict__ PBl,
                           const float* __restrict__ PBo, u16* __restrict__ CTX,
                           const int* __restrict__ obs)
{
    const int h = blockIdx.x, b = blockIdx.y, l = threadIdx.x;
    const int L = obs[b];
    const int nc = (L >> 6) + 1;
    const int base = (b * 8 + h) * 32;
    float m = -3.0e38f;
    for (int c = 0; c < nc; ++c) m = fmaxf(m, PBm[base + c]);
    float lt = 0.f, ot = 0.f;
    for (int c = 0; c < nc; ++c) {
        const float sc = __expf(PBm[base + c] - m);
        lt += sc * PBl[base + c];
        ot += sc * PBo[(size_t)(base + c) * 64 + l];
    }
    CTX[((size_t)b * 2048 + L) * 512 + h * 64 + l] = f2bf(ot / lt);
}

// ---------------------------------------------------------------------------
__global__ __launch_bounds__(256) void ln_kernel(
    const float* __restrict__ Y, const float* __restrict__ gw,
    const float* __restrict__ bw, float* __restrict__ X, u16* __restrict__ Xb,
    const int* __restrict__ obs)
{
    const int tok0 = blockIdx.x * 4;
    if ((tok0 & 2047) > obs[tok0 >> 11]) return;
    const int tok = tok0 + (threadIdx.x >> 6);
    const int l = threadIdx.x & 63;
    const float* y = &Y[(size_t)tok * 512 + l * 8];
    f32x4 v0 = *(const f32x4*)y;
    f32x4 v1 = *(const f32x4*)(y + 4);
    float s = 0.f, sq = 0.f;
    #pragma unroll
    for (int e = 0; e < 4; ++e) {
        s += v0[e] + v1[e];
        sq += v0[e] * v0[e] + v1[e] * v1[e];
    }
    #pragma unroll
    for (int d = 1; d < 64; d <<= 1) {
        s += __shfl_xor(s, d, 64);
        sq += __shfl_xor(sq, d, 64);
    }
    const float mean = s * (1.f / 512.f);
    const float var = sq * (1.f / 512.f) - mean * mean;
    const float rstd = rsqrtf(var + 1e-5f);
    f32x4 o0, o1;
    union { u16 us[8]; uint4 u4; } pk;
    #pragma unroll
    for (int e = 0; e < 8; ++e) {
        const int d = l * 8 + e;
        const float xv = (e < 4) ? v0[e] : v1[e - 4];
        const float ov = (xv - mean) * rstd * gw[d] + bw[d];
        if (e < 4) o0[e] = ov; else o1[e - 4] = ov;
        pk.us[e] = f2bf(ov);
    }
    float* xo = &X[(size_t)tok * 512 + l * 8];
    *(f32x4*)xo = o0;
    *(f32x4*)(xo + 4) = o1;
    *(uint4*)&Xb[(size_t)tok * 512 + l * 8] = pk.u4;
}

__global__ void cast_bf16_kernel(const float* __restrict__ in, u16* __restrict__ out,
                                 const int* __restrict__ obs, int n) {
    const int i = (blockIdx.x * 256 + threadIdx.x) * 4;
    const int tok0 = (blockIdx.x * 1024) >> 9;           // first token of block
    if ((tok0 & 2047) > obs[tok0 >> 11]) return;          // dead tokens (pad)
    if (i + 3 < n) {
        f32x4 v = *(const f32x4*)&in[i];
        union { u16 us[4]; uint2 u2; } pk;
        #pragma unroll
        for (int e = 0; e < 4; ++e) pk.us[e] = f2bf(v[e]);
        *(uint2*)&out[i] = pk.u2;
    }
}

__global__ void transpose_cast(const float* __restrict__ W, u16* __restrict__ WT, int K, int N) {
    __shared__ float t[32][33];
    const int n0 = blockIdx.x * 32, k0 = blockIdx.y * 32;
    const int tx = threadIdx.x, ty = threadIdx.y;
    #pragma unroll
    for (int r = 0; r < 32; r += 8)
        t[ty + r][tx] = W[(size_t)(k0 + ty + r) * N + n0 + tx];
    __syncthreads();
    #pragma unroll
    for (int r = 0; r < 32; r += 8)
        WT[(size_t)(n0 + ty + r) * K + k0 + tx] = f2bf(t[tx][ty + r]);
}

struct WPack { const float* src[16]; u16* dst[16]; };
__global__ void transpose_all(WPack p) {
    __shared__ float t[32][33];
    int id = blockIdx.x;
    const int lyr = id / 3072;
    id -= lyr * 3072;
    int wi, K, N;
    if (id < 768)       { wi = 0; K = 512;  N = 1536; }
    else if (id < 1024) { wi = 1; K = 512;  N = 512;  id -= 768; }
    else if (id < 2048) { wi = 2; K = 512;  N = 2048; id -= 1024; }
    else                { wi = 3; K = 2048; N = 512;  id -= 2048; }
    const float* W = p.src[lyr * 4 + wi];
    u16* D = p.dst[lyr * 4 + wi];
    const int nx = N >> 5;
    const int n0 = (id % nx) * 32, k0 = (id / nx) * 32;
    const int tx = threadIdx.x, ty = threadIdx.y;
    #pragma unroll
    for (int r = 0; r < 32; r += 8)
        t[ty + r][tx] = W[(size_t)(k0 + ty + r) * N + n0 + tx];
    __syncthreads();
    #pragma unroll
    for (int r = 0; r < 32; r += 8)
        D[(size_t)(n0 + ty + r) * K + k0 + tx] = f2bf(t[tx][ty + r]);
}

__global__ void agg_partial(const float* __restrict__ X, float* __restrict__ part,
                            const int* __restrict__ obs) {
    const int b = blockIdx.y, c = blockIdx.x, d = threadIdx.x;
    const int L = obs[b];
    float s = 0.f;
    const int t0 = c * 128;
    int tend = t0 + 128;
    if (tend > L + 1) tend = L + 1;
    for (int t = t0; t < tend; ++t) s += X[((size_t)b * 2048 + t) * 512 + d];
    part[((size_t)b * 16 + c) * 512 + d] = s;
}

__global__ void agg_final(const float* __restrict__ part, float* __restrict__ out,
                          const int* __restrict__ obs) {
    const int b = blockIdx.x, d = threadIdx.x;
    float s = 0.f;
    #pragma unroll
    for (int c = 0; c < 16; ++c) s += part[((size_t)b * 16 + c) * 512 + d];
    out[b * 512 + d] = s / (float)(obs[b] + 1);
}

// ---------------------------------------------------------------------------
extern "C" void kernel_launch(void* const* d_in, const int* in_sizes, int n_in,
                              void* d_out, int out_size, void* d_ws, size_t ws_size,
                              hipStream_t stream)
{
    const int M = 32768;        // B*T
    const int FCH = 16384;      // FF chunk rows (small-ws path)
    const bool bigws = ws_size >= (size_t)270 * 1024 * 1024;
    const float* traj = (const float*)d_in[0];
    const int* obs = (const int*)d_in[1];
    const float* w_in = (const float*)d_in[2];
    const float* b_in = (const float*)d_in[3];

    char* base = (char*)d_ws;
    size_t off = 0;
    auto carve = [&](size_t bytes) -> void* {
        void* p = base + off;
        off += (bytes + 255) & ~(size_t)255;
        return p;
    };
    u16* U     = (u16*)carve((size_t)M * (bigws ? 2048 : 1536) * 2);
    u16* Xb    = (u16*)carve((size_t)M * 512 * 2);
    float* X   = (float*)carve((size_t)M * 512 * 4);
    float* PE  = (float*)carve((size_t)2048 * 512 * 4);
    float* PBm = (float*)carve((size_t)16 * 8 * 32 * 4);
    float* PBl = (float*)carve((size_t)16 * 8 * 32 * 4);
    float* PBo = (float*)carve((size_t)16 * 8 * 32 * 64 * 4);
    float* part = (float*)carve((size_t)16 * 16 * 512 * 4);
    u16* wTin  = (u16*)carve((size_t)512 * 512 * 2);
    u16 *wqkv[4], *wo[4], *wff1[4], *wff2[4];
    for (int l = 0; l < 4; ++l) {
        wqkv[l] = (u16*)carve((size_t)1536 * 512 * 2);
        wo[l]   = (u16*)carve((size_t)512 * 512 * 2);
        wff1[l] = (u16*)carve((size_t)2048 * 512 * 2);
        wff2[l] = (u16*)carve((size_t)512 * 2048 * 2);
    }

    dim3 tb32(32, 8);
    pe_kernel<<<2048, 256, 0, stream>>>(PE);
    transpose_cast<<<dim3(16, 16), tb32, 0, stream>>>(w_in, wTin, 512, 512);
    {
        WPack p;
        for (int l = 0; l < 4; ++l) {
            const int bi = 4 + 12 * l;
            p.src[l * 4 + 0] = (const float*)d_in[bi + 0];
            p.src[l * 4 + 1] = (const float*)d_in[bi + 2];
            p.src[l * 4 + 2] = (const float*)d_in[bi + 4];
            p.src[l * 4 + 3] = (const float*)d_in[bi + 6];
            p.dst[l * 4 + 0] = wqkv[l];
            p.dst[l * 4 + 1] = wo[l];
            p.dst[l * 4 + 2] = wff1[l];
            p.dst[l * 4 + 3] = wff2[l];
        }
        transpose_all<<<12288, tb32, 0, stream>>>(p);
    }

    cast_bf16_kernel<<<(M * 512) / 1024, 256, 0, stream>>>(traj, U, obs, M * 512);
    gemm_bf16<0, 64><<<dim3(4, M / 128), 256, 0, stream>>>(
        U, wTin, b_in, X, Xb, PE, obs, M, 512, 512);

    for (int lyr = 0; lyr < 4; ++lyr) {
        const int bi = 4 + 12 * lyr;
        const float* b_qkv = (const float*)d_in[bi + 1];
        const float* b_o   = (const float*)d_in[bi + 3];
        const float* b_ff1 = (const float*)d_in[bi + 5];
        const float* b_ff2 = (const float*)d_in[bi + 7];
        const float* ln1g  = (const float*)d_in[bi + 8];
        const float* ln1b  = (const float*)d_in[bi + 9];
        const float* ln2g  = (const float*)d_in[bi + 10];
        const float* ln2b  = (const float*)d_in[bi + 11];

        gemm_bf16<1, 32><<<dim3(12, M / 128), 256, 0, stream>>>(
            Xb, wqkv[lyr], b_qkv, nullptr, U, nullptr, obs, M, 1536, 512);
        attn_kernel<<<dim3(40, 8, 16), 256, 0, stream>>>(U, Xb, obs, PBm, PBl, PBo);
        attn_merge<<<dim3(8, 16), 64, 0, stream>>>(PBm, PBl, PBo, Xb, obs);
        gemm_bf16<2, 64><<<dim3(4, M / 128), 256, 0, stream>>>(
            Xb, wo[lyr], b_o, X, nullptr, X, obs, M, 512, 512);
        ln_kernel<<<M / 4, 256, 0, stream>>>(X, ln1g, ln1b, X, Xb, obs);
        if (bigws) {
            gemm_bf16<3, 32><<<dim3(16, M / 128), 256, 0, stream>>>(
                Xb, wff1[lyr], b_ff1, nullptr, U, nullptr, obs, M, 2048, 512);
            gemm_bf16<2, 64><<<dim3(4, M / 128), 256, 0, stream>>>(
                U, wff2[lyr], b_ff2, X, nullptr, X, obs, M, 512, 2048);
        } else {
            for (int c = 0; c < 2; ++c) {
                gemm_bf16<3, 32><<<dim3(16, FCH / 128), 256, 0, stream>>>(
                    Xb + (size_t)c * FCH * 512, wff1[lyr], b_ff1, nullptr, U, nullptr,
                    obs + c * 8, FCH, 2048, 512);
                gemm_bf16<2, 64><<<dim3(4, FCH / 128), 256, 0, stream>>>(
                    U, wff2[lyr], b_ff2, X + (size_t)c * FCH * 512, nullptr,
                    X + (size_t)c * FCH * 512, obs + c * 8, FCH, 512, 2048);
            }
        }
        ln_kernel<<<M / 4, 256, 0, stream>>>(X, ln2g, ln2b, X, Xb, obs);
    }

    agg_partial<<<dim3(16, 16), 512, 0, stream>>>(X, part, obs);
    agg_final<<<16, 512, 0, stream>>>(part, (float*)d_out, obs);
}

// Round 17
// 1245.635 us; speedup vs baseline: 1.0068x; 1.0068x over previous
//
#include <hip/hip_runtime.h>

typedef unsigned short u16;
typedef unsigned int u32;
typedef __bf16 bf16x8 __attribute__((ext_vector_type(8)));
typedef float f32x4 __attribute__((ext_vector_type(4)));

#define MFMA16(a, b, c) __builtin_amdgcn_mfma_f32_16x16x32_bf16((a), (b), (c), 0, 0, 0)

__device__ __forceinline__ u16 f2bf(float x) {
    union { float f; u32 u; } v; v.f = x;
    u32 r = v.u + 0x7fffu + ((v.u >> 16) & 1u);
    return (u16)(r >> 16);
}
__device__ __forceinline__ float bf2f(u16 x) {
    union { u32 u; float f; } v; v.u = ((u32)x) << 16; return v.f;
}

typedef const __attribute__((address_space(1))) u32* gas1_t;
typedef __attribute__((address_space(3))) u32* las3_t;
__device__ __forceinline__ void g2lds16(const void* g, void* l) {
    __builtin_amdgcn_global_load_lds((gas1_t)g, (las3_t)l, 16, 0, 0);
}

// ---------------------------------------------------------------------------
// GEMM (exact round-15 best-measured configuration):
// m97 fragment layout + 2-phase dbuf staging + dead-tile skip + balanced XCD
// mapping (xcd(tm)=(tm+batch)&7, bijective for gy%16==0).
// BK=32 (wide N): rule-21 swizzle, 0 conflicts (measured r12/r15).
// BK=64 (narrow N=512): r8 path w/ swizzle, 0 conflicts (measured r10).
// Direct epilogue (LDS-repack variant measured WORSE in r16: +2 barriers,
// +196K conflicts, qkv 51->60us — scalar bf16 stores are NOT the bottleneck).
// MODE 0: +=PE, f32+bf16 out. 1: bf16. 2: +=resid, f32. 3: relu bf16.
// ---------------------------------------------------------------------------
template <int MODE, int BK>
__global__ __launch_bounds__(256) void gemm_bf16(
    const u16* __restrict__ A, const u16* __restrict__ BT,
    const float* __restrict__ bias, float* __restrict__ outF,
    u16* __restrict__ outB, const float* __restrict__ aux,
    const int* __restrict__ obs,
    int M, int N, int K)
{
    __shared__ u16 As[2][128 * BK];
    __shared__ u16 Bs[2][128 * BK];
    const int tid = threadIdx.x;
    const int w = tid >> 6, l = tid & 63;
    const int gx = gridDim.x, gy = gridDim.y;
    const int orig = blockIdx.y * gx + blockIdx.x;
    int tm, tn;
    if ((gy & 15) == 0) {
        const int xcd = orig & 7;
        const int loc = orig >> 3;
        tn = loc % gx;
        const int j = loc / gx;
        const int bb = j >> 1;
        tm = bb * 16 + ((xcd - bb) & 7) + ((j & 1) << 3);
    } else {
        tm = blockIdx.y; tn = blockIdx.x;
    }
    const int bm = tm * 128, bn = tn * 128;
    if ((bm & 2047) > obs[bm >> 11]) return;   // dead tile (pad rows only)
    const int wr = (w >> 1) * 64, wc = (w & 1) * 64;
    f32x4 acc[4][4] = {};
    const int lane15 = l & 15, lhi = l >> 4;

    // --- staging (linear LDS dest + pre-swizzled global source, rule 21) ---
    const int larow = l >> 2;                                     // BK=32
    const int lacol = (((l & 3) ^ ((l >> 3) & 3)) << 3);
    const int gsw32 = ((lhi ^ ((lane15 >> 1) & 3)) << 3);
    const int r0a = 16 * w, r0b = 16 * (w + 4);
    const u16* Ap = &A[(size_t)(bm + larow) * K + lacol];
    const u16* Bp = &BT[(size_t)(bn + larow) * K + lacol];
    const int srow = l >> 3;                                      // BK=64
    const int scol = ((l & 7) ^ srow) << 3;

    auto STAGE = [&](int buf, int kt) {
        if constexpr (BK == 32) {
            g2lds16(Ap + (size_t)r0a * K + kt, &As[buf][r0a * 32]);
            g2lds16(Bp + (size_t)r0a * K + kt, &Bs[buf][r0a * 32]);
            g2lds16(Ap + (size_t)r0b * K + kt, &As[buf][r0b * 32]);
            g2lds16(Bp + (size_t)r0b * K + kt, &Bs[buf][r0b * 32]);
        } else {
            #pragma unroll
            for (int q = 0; q < 4; ++q) {
                const int rr = w * 32 + q * 8;
                g2lds16(&A[(size_t)(bm + rr + srow) * K + kt + scol], &As[buf][rr * 64]);
                g2lds16(&BT[(size_t)(bn + rr + srow) * K + kt + scol], &Bs[buf][rr * 64]);
            }
        }
    };

    STAGE(0, 0);
    __syncthreads();
    int cur = 0;
    const int nk = K / BK;
    for (int ki = 0; ki < nk; ++ki) {
        if (ki + 1 < nk) STAGE(cur ^ 1, (ki + 1) * BK);
        if constexpr (BK == 32) {
            bf16x8 af[4], bfr[4];
            #pragma unroll
            for (int i = 0; i < 4; ++i)
                af[i] = *(const bf16x8*)&As[cur][(wr + i * 16 + lane15) * 32 + gsw32];
            #pragma unroll
            for (int j = 0; j < 4; ++j)
                bfr[j] = *(const bf16x8*)&Bs[cur][(wc + j * 16 + lane15) * 32 + gsw32];
            #pragma unroll
            for (int i = 0; i < 4; ++i)
                #pragma unroll
                for (int j = 0; j < 4; ++j)
                    acc[i][j] = MFMA16(af[i], bfr[j], acc[i][j]);
        } else {
            #pragma unroll
            for (int kk = 0; kk < 2; ++kk) {
                const int gsw = ((kk * 4 + lhi) ^ (l & 7)) << 3;
                bf16x8 af[4], bfr[4];
                #pragma unroll
                for (int i = 0; i < 4; ++i)
                    af[i] = *(const bf16x8*)&As[cur][(wr + i * 16 + lane15) * 64 + gsw];
                #pragma unroll
                for (int j = 0; j < 4; ++j)
                    bfr[j] = *(const bf16x8*)&Bs[cur][(wc + j * 16 + lane15) * 64 + gsw];
                #pragma unroll
                for (int i = 0; i < 4; ++i)
                    #pragma unroll
                    for (int j = 0; j < 4; ++j)
                        acc[i][j] = MFMA16(af[i], bfr[j], acc[i][j]);
            }
        }
        __syncthreads();
        cur ^= 1;
    }

    const int r0 = bm + wr + lhi * 4;
    const int c0 = bn + wc + lane15;
    #pragma unroll
    for (int i = 0; i < 4; ++i) {
        #pragma unroll
        for (int j = 0; j < 4; ++j) {
            const int col = c0 + j * 16;
            const float bc = bias[col];
            #pragma unroll
            for (int r = 0; r < 4; ++r) {
                const int row = r0 + i * 16 + r;
                const size_t idx = (size_t)row * N + col;
                float val = acc[i][j][r] + bc;
                if constexpr (MODE == 0) {
                    val += aux[(size_t)(row & 2047) * 512 + col];
                    outF[idx] = val;
                    outB[idx] = f2bf(val);
                } else if constexpr (MODE == 1) {
                    outB[idx] = f2bf(val);
                } else if constexpr (MODE == 2) {
                    outF[idx] = val + aux[idx];
                } else {
                    outB[idx] = f2bf(fmaxf(val, 0.f));
                }
            }
        }
    }
}

__global__ void pe_kernel(float* __restrict__ PE) {
    const int idx = blockIdx.x * 256 + threadIdx.x;
    const int t = idx >> 8, p = idx & 255;
    const float fr = expf((float)(2 * p) * -0.017988946039015984f);
    const float arg = (float)t * fr;
    float s, c;
    sincosf(arg, &s, &c);
    float2 v = {s, c};
    *(float2*)&PE[(size_t)t * 512 + 2 * p] = v;
}

// ---------------------------------------------------------------------------
// Flash attention (round-8 version, unchanged).
// ---------------------------------------------------------------------------
__global__ __launch_bounds__(256) void attn_kernel(
    const u16* __restrict__ QKV, u16* __restrict__ CTX, const int* __restrict__ obs,
    float* __restrict__ PBm, float* __restrict__ PBl, float* __restrict__ PBo)
{
    __shared__ u16 Ks[64 * 64];
    __shared__ u16 Vt[64 * 64];
    __shared__ u16 Ps[4][16 * 64];
    const int b = blockIdx.z, h = blockIdx.y;
    const int L = obs[b];
    const int tid = threadIdx.x, w = tid >> 6, l = tid & 63;
    const size_t tb = (size_t)b * 2048;

    if (blockIdx.x >= 32) {
        const int cbase = (blockIdx.x - 32) * 4;
        if (cbase * 64 > L) return;
        const int cc = cbase + w;
        float* pP = (float*)Ks;
        u16 q16[64];
        #pragma unroll
        for (int dd = 0; dd < 8; ++dd)
            *(uint4*)&q16[dd * 8] = *(const uint4*)&QKV[(tb + L) * 1536 + h * 64 + dd * 8];
        const int j = cc * 64 + l;
        const bool val = (j <= L);
        float s = -3.0e38f;
        if (val) {
            s = 0.f;
            const u16* kp = &QKV[(tb + j) * 1536 + 512 + h * 64];
            #pragma unroll
            for (int dd = 0; dd < 8; ++dd) {
                uint4 kk = *(const uint4*)&kp[dd * 8];
                const u16* ke = (const u16*)&kk;
                #pragma unroll
                for (int e = 0; e < 8; ++e)
                    s += bf2f(q16[dd * 8 + e]) * bf2f(ke[e]);
            }
            s *= 0.125f;
        }
        float mx = s;
        #pragma unroll
        for (int d = 1; d < 64; d <<= 1) mx = fmaxf(mx, __shfl_xor(mx, d, 64));
        const float p = val ? __expf(s - mx) : 0.f;
        float ps = p;
        #pragma unroll
        for (int d = 1; d < 64; d <<= 1) ps += __shfl_xor(ps, d, 64);
        pP[w * 64 + l] = p;
        __builtin_amdgcn_wave_barrier();
        if (cc * 64 <= L) {
            float oacc = 0.f;
            #pragma unroll 4
            for (int jj = 0; jj < 64; ++jj) {
                const int key = cc * 64 + jj;
                const int rr = (key <= L) ? key : L;
                oacc += pP[w * 64 + jj] * bf2f(QKV[(tb + rr) * 1536 + 1024 + h * 64 + l]);
            }
            const int pidx = (b * 8 + h) * 32 + cc;
            PBo[(size_t)pidx * 64 + l] = oacc;
            if (l == 0) { PBm[pidx] = mx; PBl[pidx] = ps; }
        }
        return;
    }

    const int i0 = blockIdx.x * 64;
    if (i0 > L) return;

    bf16x8 qa0, qa1;
    {
        const int qrow = i0 + 16 * w + (l & 15);
        const u16* qp = &QKV[(tb + qrow) * 1536 + h * 64];
        qa0 = *(const bf16x8*)(qp + 8 * (l >> 4));
        qa1 = *(const bf16x8*)(qp + 32 + 8 * (l >> 4));
    }
    const int g0 = (l >> 4) ^ (l & 7);
    const int g1 = ((l >> 4) + 4) ^ (l & 7);

    float m_r[4] = {-1e30f, -1e30f, -1e30f, -1e30f};
    float l_r[4] = {0.f, 0.f, 0.f, 0.f};
    f32x4 acc_o[4] = {};
    const int klo = (i0 >= 128) ? (i0 - 64) : 0;
    int khi = (L < klo) ? klo : min(i0 + 63, L);

    for (int j0 = klo; j0 <= khi; j0 += 64) {
        __syncthreads();
        {
            const int krow0 = 8 * w + (l >> 3);
            const int kswz = ((l & 7) ^ (l >> 3)) << 3;
            #pragma unroll
            for (int q = 0; q < 2; ++q) {
                const int row = krow0 + 32 * q;
                g2lds16(&QKV[(tb + j0 + row) * 1536 + 512 + h * 64 + kswz],
                        &Ks[(8 * w + 32 * q) * 64]);
            }
            const int vr = tid >> 3, c8 = (tid & 7) * 8;
            #pragma unroll
            for (int q = 0; q < 2; ++q) {
                const int row = vr + 32 * q;
                uint4 vv = *(const uint4*)&QKV[(tb + j0 + row) * 1536 + 1024 + h * 64 + c8];
                const u16* vs = (const u16*)&vv;
                #pragma unroll
                for (int e = 0; e < 8; ++e) {
                    const int d = c8 + e;
                    Vt[d * 64 + (((row >> 3) ^ e) << 3) + (row & 7)] = vs[e];
                }
            }
        }
        __syncthreads();
        f32x4 s[4];
        #pragma unroll
        for (int f = 0; f < 4; ++f) {
            f32x4 z = {0.f, 0.f, 0.f, 0.f};
            const int rowk = (f * 16 + (l & 15)) * 64;
            bf16x8 kb0 = *(const bf16x8*)&Ks[rowk + g0 * 8];
            bf16x8 kb1 = *(const bf16x8*)&Ks[rowk + g1 * 8];
            z = MFMA16(qa0, kb0, z);
            z = MFMA16(qa1, kb1, z);
            s[f] = z;
        }
        float pm[4];
        #pragma unroll
        for (int r = 0; r < 4; ++r) {
            const int i_r = i0 + 16 * w + (l >> 4) * 4 + r;
            float mx = -__builtin_inff();
            #pragma unroll
            for (int f = 0; f < 4; ++f) {
                const int j = j0 + f * 16 + (l & 15);
                float sv = s[f][r] * 0.125f;
                const bool ok = (i_r >= L) ? (j == klo)
                              : (j <= i_r && (i_r <= 64 || j >= i_r - 64));
                sv = ok ? sv : -__builtin_inff();
                s[f][r] = sv;
                mx = fmaxf(mx, sv);
            }
            pm[r] = mx;
        }
        #pragma unroll
        for (int d = 1; d < 16; d <<= 1)
            #pragma unroll
            for (int r = 0; r < 4; ++r) pm[r] = fmaxf(pm[r], __shfl_xor(pm[r], d, 64));
        float sc[4];
        #pragma unroll
        for (int r = 0; r < 4; ++r) {
            const float mn = fmaxf(m_r[r], fmaxf(pm[r], -1e30f));
            sc[r] = __expf(m_r[r] - mn);
            m_r[r] = mn;
            l_r[r] *= sc[r];
        }
        #pragma unroll
        for (int f = 0; f < 4; ++f)
            #pragma unroll
            for (int r = 0; r < 4; ++r) acc_o[f][r] *= sc[r];
        float ps[4] = {0.f, 0.f, 0.f, 0.f};
        #pragma unroll
        for (int f = 0; f < 4; ++f)
            #pragma unroll
            for (int r = 0; r < 4; ++r) {
                const float p = __expf(s[f][r] - m_r[r]);
                s[f][r] = p;
                ps[r] += p;
            }
        #pragma unroll
        for (int d = 1; d < 16; d <<= 1)
            #pragma unroll
            for (int r = 0; r < 4; ++r) ps[r] += __shfl_xor(ps[r], d, 64);
        #pragma unroll
        for (int r = 0; r < 4; ++r) l_r[r] += ps[r];
        {
            const int cg = ((l >> 3) & 1);
            #pragma unroll
            for (int f = 0; f < 4; ++f)
                #pragma unroll
                for (int r = 0; r < 4; ++r) {
                    const int prow = (l >> 4) * 4 + r;
                    Ps[w][prow * 64 + (((f * 2 + cg) ^ (prow & 7)) << 3) + (l & 7)] =
                        f2bf(s[f][r]);
                }
        }
        bf16x8 pa0 = *(const bf16x8*)&Ps[w][(l & 15) * 64 + g0 * 8];
        bf16x8 pa1 = *(const bf16x8*)&Ps[w][(l & 15) * 64 + g1 * 8];
        #pragma unroll
        for (int f = 0; f < 4; ++f) {
            const int dv = (f * 16 + (l & 15)) * 64;
            bf16x8 vb0 = *(const bf16x8*)&Vt[dv + g0 * 8];
            bf16x8 vb1 = *(const bf16x8*)&Vt[dv + g1 * 8];
            acc_o[f] = MFMA16(pa0, vb0, acc_o[f]);
            acc_o[f] = MFMA16(pa1, vb1, acc_o[f]);
        }
    }
    #pragma unroll
    for (int r = 0; r < 4; ++r) {
        const float inv = 1.f / l_r[r];
        const int row = i0 + 16 * w + (l >> 4) * 4 + r;
        if (row != L) {
            #pragma unroll
            for (int f = 0; f < 4; ++f)
                CTX[(tb + row) * 512 + h * 64 + f * 16 + (l & 15)] = f2bf(acc_o[f][r] * inv);
        }
    }
}

__global__ void attn_merge(const float* __restrict__ PBm, const float* __restrict__ PBl,
                           const float* __restrict__ PBo, u16* __restrict__ CTX,
                           const int* __restrict__ obs)
{
    const int h = blockIdx.x, b = blockIdx.y, l = threadIdx.x;
    const int L = obs[b];
    const int nc = (L >> 6) + 1;
    const int base = (b * 8 + h) * 32;
    float m = -3.0e38f;
    for (int c = 0; c < nc; ++c) m = fmaxf(m, PBm[base + c]);
    float lt = 0.f, ot = 0.f;
    for (int c = 0; c < nc; ++c) {
        const float sc = __expf(PBm[base + c] - m);
        lt += sc * PBl[base + c];
        ot += sc * PBo[(size_t)(base + c) * 64 + l];
    }
    CTX[((size_t)b * 2048 + L) * 512 + h * 64 + l] = f2bf(ot / lt);
}

// ---------------------------------------------------------------------------
__global__ __launch_bounds__(256) void ln_kernel(
    const float* __restrict__ Y, const float* __restrict__ gw,
    const float* __restrict__ bw, float* __restrict__ X, u16* __restrict__ Xb,
    const int* __restrict__ obs)
{
    const int tok0 = blockIdx.x * 4;
    if ((tok0 & 2047) > obs[tok0 >> 11]) return;
    const int tok = tok0 + (threadIdx.x >> 6);
    const int l = threadIdx.x & 63;
    const float* y = &Y[(size_t)tok * 512 + l * 8];
    f32x4 v0 = *(const f32x4*)y;
    f32x4 v1 = *(const f32x4*)(y + 4);
    float s = 0.f, sq = 0.f;
    #pragma unroll
    for (int e = 0; e < 4; ++e) {
        s += v0[e] + v1[e];
        sq += v0[e] * v0[e] + v1[e] * v1[e];
    }
    #pragma unroll
    for (int d = 1; d < 64; d <<= 1) {
        s += __shfl_xor(s, d, 64);
        sq += __shfl_xor(sq, d, 64);
    }
    const float mean = s * (1.f / 512.f);
    const float var = sq * (1.f / 512.f) - mean * mean;
    const float rstd = rsqrtf(var + 1e-5f);
    f32x4 o0, o1;
    union { u16 us[8]; uint4 u4; } pk;
    #pragma unroll
    for (int e = 0; e < 8; ++e) {
        const int d = l * 8 + e;
        const float xv = (e < 4) ? v0[e] : v1[e - 4];
        const float ov = (xv - mean) * rstd * gw[d] + bw[d];
        if (e < 4) o0[e] = ov; else o1[e - 4] = ov;
        pk.us[e] = f2bf(ov);
    }
    float* xo = &X[(size_t)tok * 512 + l * 8];
    *(f32x4*)xo = o0;
    *(f32x4*)(xo + 4) = o1;
    *(uint4*)&Xb[(size_t)tok * 512 + l * 8] = pk.u4;
}

__global__ void cast_bf16_kernel(const float* __restrict__ in, u16* __restrict__ out,
                                 const int* __restrict__ obs, int n) {
    const int i = (blockIdx.x * 256 + threadIdx.x) * 4;
    const int tok0 = (blockIdx.x * 1024) >> 9;           // first token of block
    if ((tok0 & 2047) > obs[tok0 >> 11]) return;          // dead tokens (pad)
    if (i + 3 < n) {
        f32x4 v = *(const f32x4*)&in[i];
        union { u16 us[4]; uint2 u2; } pk;
        #pragma unroll
        for (int e = 0; e < 4; ++e) pk.us[e] = f2bf(v[e]);
        *(uint2*)&out[i] = pk.u2;
    }
}

__global__ void transpose_cast(const float* __restrict__ W, u16* __restrict__ WT, int K, int N) {
    __shared__ float t[32][33];
    const int n0 = blockIdx.x * 32, k0 = blockIdx.y * 32;
    const int tx = threadIdx.x, ty = threadIdx.y;
    #pragma unroll
    for (int r = 0; r < 32; r += 8)
        t[ty + r][tx] = W[(size_t)(k0 + ty + r) * N + n0 + tx];
    __syncthreads();
    #pragma unroll
    for (int r = 0; r < 32; r += 8)
        WT[(size_t)(n0 + ty + r) * K + k0 + tx] = f2bf(t[tx][ty + r]);
}

struct WPack { const float* src[16]; u16* dst[16]; };
__global__ void transpose_all(WPack p) {
    __shared__ float t[32][33];
    int id = blockIdx.x;
    const int lyr = id / 3072;
    id -= lyr * 3072;
    int wi, K, N;
    if (id < 768)       { wi = 0; K = 512;  N = 1536; }
    else if (id < 1024) { wi = 1; K = 512;  N = 512;  id -= 768; }
    else if (id < 2048) { wi = 2; K = 512;  N = 2048; id -= 1024; }
    else                { wi = 3; K = 2048; N = 512;  id -= 2048; }
    const float* W = p.src[lyr * 4 + wi];
    u16* D = p.dst[lyr * 4 + wi];
    const int nx = N >> 5;
    const int n0 = (id % nx) * 32, k0 = (id / nx) * 32;
    const int tx = threadIdx.x, ty = threadIdx.y;
    #pragma unroll
    for (int r = 0; r < 32; r += 8)
        t[ty + r][tx] = W[(size_t)(k0 + ty + r) * N + n0 + tx];
    __syncthreads();
    #pragma unroll
    for (int r = 0; r < 32; r += 8)
        D[(size_t)(n0 + ty + r) * K + k0 + tx] = f2bf(t[tx][ty + r]);
}

__global__ void agg_partial(const float* __restrict__ X, float* __restrict__ part,
                            const int* __restrict__ obs) {
    const int b = blockIdx.y, c = blockIdx.x, d = threadIdx.x;
    const int L = obs[b];
    float s = 0.f;
    const int t0 = c * 128;
    int tend = t0 + 128;
    if (tend > L + 1) tend = L + 1;
    for (int t = t0; t < tend; ++t) s += X[((size_t)b * 2048 + t) * 512 + d];
    part[((size_t)b * 16 + c) * 512 + d] = s;
}

__global__ void agg_final(const float* __restrict__ part, float* __restrict__ out,
                          const int* __restrict__ obs) {
    const int b = blockIdx.x, d = threadIdx.x;
    float s = 0.f;
    #pragma unroll
    for (int c = 0; c < 16; ++c) s += part[((size_t)b * 16 + c) * 512 + d];
    out[b * 512 + d] = s / (float)(obs[b] + 1);
}

// ---------------------------------------------------------------------------
extern "C" void kernel_launch(void* const* d_in, const int* in_sizes, int n_in,
                              void* d_out, int out_size, void* d_ws, size_t ws_size,
                              hipStream_t stream)
{
    const int M = 32768;        // B*T
    const int FCH = 16384;      // FF chunk rows (small-ws path)
    const bool bigws = ws_size >= (size_t)270 * 1024 * 1024;
    const float* traj = (const float*)d_in[0];
    const int* obs = (const int*)d_in[1];
    const float* w_in = (const float*)d_in[2];
    const float* b_in = (const float*)d_in[3];

    char* base = (char*)d_ws;
    size_t off = 0;
    auto carve = [&](size_t bytes) -> void* {
        void* p = base + off;
        off += (bytes + 255) & ~(size_t)255;
        return p;
    };
    u16* U     = (u16*)carve((size_t)M * (bigws ? 2048 : 1536) * 2);
    u16* Xb    = (u16*)carve((size_t)M * 512 * 2);
    float* X   = (float*)carve((size_t)M * 512 * 4);
    float* PE  = (float*)carve((size_t)2048 * 512 * 4);
    float* PBm = (float*)carve((size_t)16 * 8 * 32 * 4);
    float* PBl = (float*)carve((size_t)16 * 8 * 32 * 4);
    float* PBo = (float*)carve((size_t)16 * 8 * 32 * 64 * 4);
    float* part = (float*)carve((size_t)16 * 16 * 512 * 4);
    u16* wTin  = (u16*)carve((size_t)512 * 512 * 2);
    u16 *wqkv[4], *wo[4], *wff1[4], *wff2[4];
    for (int l = 0; l < 4; ++l) {
        wqkv[l] = (u16*)carve((size_t)1536 * 512 * 2);
        wo[l]   = (u16*)carve((size_t)512 * 512 * 2);
        wff1[l] = (u16*)carve((size_t)2048 * 512 * 2);
        wff2[l] = (u16*)carve((size_t)512 * 2048 * 2);
    }

    dim3 tb32(32, 8);
    pe_kernel<<<2048, 256, 0, stream>>>(PE);
    transpose_cast<<<dim3(16, 16), tb32, 0, stream>>>(w_in, wTin, 512, 512);
    {
        WPack p;
        for (int l = 0; l < 4; ++l) {
            const int bi = 4 + 12 * l;
            p.src[l * 4 + 0] = (const float*)d_in[bi + 0];
            p.src[l * 4 + 1] = (const float*)d_in[bi + 2];
            p.src[l * 4 + 2] = (const float*)d_in[bi + 4];
            p.src[l * 4 + 3] = (const float*)d_in[bi + 6];
            p.dst[l * 4 + 0] = wqkv[l];
            p.dst[l * 4 + 1] = wo[l];
            p.dst[l * 4 + 2] = wff1[l];
            p.dst[l * 4 + 3] = wff2[l];
        }
        transpose_all<<<12288, tb32, 0, stream>>>(p);
    }

    cast_bf16_kernel<<<(M * 512) / 1024, 256, 0, stream>>>(traj, U, obs, M * 512);
    gemm_bf16<0, 64><<<dim3(4, M / 128), 256, 0, stream>>>(
        U, wTin, b_in, X, Xb, PE, obs, M, 512, 512);

    for (int lyr = 0; lyr < 4; ++lyr) {
        const int bi = 4 + 12 * lyr;
        const float* b_qkv = (const float*)d_in[bi + 1];
        const float* b_o   = (const float*)d_in[bi + 3];
        const float* b_ff1 = (const float*)d_in[bi + 5];
        const float* b_ff2 = (const float*)d_in[bi + 7];
        const float* ln1g  = (const float*)d_in[bi + 8];
        const float* ln1b  = (const float*)d_in[bi + 9];
        const float* ln2g  = (const float*)d_in[bi + 10];
        const float* ln2b  = (const float*)d_in[bi + 11];

        gemm_bf16<1, 32><<<dim3(12, M / 128), 256, 0, stream>>>(
            Xb, wqkv[lyr], b_qkv, nullptr, U, nullptr, obs, M, 1536, 512);
        attn_kernel<<<dim3(40, 8, 16), 256, 0, stream>>>(U, Xb, obs, PBm, PBl, PBo);
        attn_merge<<<dim3(8, 16), 64, 0, stream>>>(PBm, PBl, PBo, Xb, obs);
        gemm_bf16<2, 64><<<dim3(4, M / 128), 256, 0, stream>>>(
            Xb, wo[lyr], b_o, X, nullptr, X, obs, M, 512, 512);
        ln_kernel<<<M / 4, 256, 0, stream>>>(X, ln1g, ln1b, X, Xb, obs);
        if (bigws) {
            gemm_bf16<3, 32><<<dim3(16, M / 128), 256, 0, stream>>>(
                Xb, wff1[lyr], b_ff1, nullptr, U, nullptr, obs, M, 2048, 512);
            gemm_bf16<2, 64><<<dim3(4, M / 128), 256, 0, stream>>>(
                U, wff2[lyr], b_ff2, X, nullptr, X, obs, M, 512, 2048);
        } else {
            for (int c = 0; c < 2; ++c) {
                gemm_bf16<3, 32><<<dim3(16, FCH / 128), 256, 0, stream>>>(
                    Xb + (size_t)c * FCH * 512, wff1[lyr], b_ff1, nullptr, U, nullptr,
                    obs + c * 8, FCH, 2048, 512);
                gemm_bf16<2, 64><<<dim3(4, FCH / 128), 256, 0, stream>>>(
                    U, wff2[lyr], b_ff2, X + (size_t)c * FCH * 512, nullptr,
                    X + (size_t)c * FCH * 512, obs + c * 8, FCH, 512, 2048);
            }
        }
        ln_kernel<<<M / 4, 256, 0, stream>>>(X, ln2g, ln2b, X, Xb, obs);
    }

    agg_partial<<<dim3(16, 16), 512, 0, stream>>>(X, part, obs);
    agg_final<<<16, 512, 0, stream>>>(part, (float*)d_out, obs);
}